// Round 1
// baseline (4893.807 us; speedup 1.0000x reference)
//
#include <hip/hip_runtime.h>
#include <stdint.h>

#define B_ 64
#define S_ 512
#define I_ 512
#define H_ 1024
#define O_ 512
#define HB (B_ * H_)   // 65536 elements per hs slot

typedef __attribute__((ext_vector_type(8))) short bf16x8;   // 8 bf16 in 4 VGPRs
typedef __attribute__((ext_vector_type(4))) float f32x4;

__device__ inline unsigned short f2bf(float f) {
    union { float f; unsigned u; } v; v.f = f;
    unsigned r = v.u + 0x7fffu + ((v.u >> 16) & 1u);   // RNE
    return (unsigned short)(r >> 16);
}
__device__ inline float bf2f(unsigned short h) {
    union { unsigned u; float f; } v; v.u = ((unsigned)h) << 16; return v.f;
}

// ---------------- fp32 -> bf16 convert (x4 vectorized) ----------------
__global__ void k_f2bf4(const float4* __restrict__ src, ushort4* __restrict__ dst, int n4) {
    int i = blockIdx.x * blockDim.x + threadIdx.x;
    if (i < n4) {
        float4 v = src[i];
        ushort4 o;
        o.x = f2bf(v.x); o.y = f2bf(v.y); o.z = f2bf(v.z); o.w = f2bf(v.w);
        dst[i] = o;
    }
}

// ---------------- init: hs slot 0 = 0 (h0), ctr = 0 ----------------
__global__ void k_init(unsigned short* __restrict__ hs0, int* __restrict__ ctr) {
    int i = blockIdx.x * blockDim.x + threadIdx.x;
    if (i < HB) hs0[i] = 0;
    if (i < S_) ctr[i] = 0;
}

// ---------------- generic 128x128 bf16 MFMA GEMM: C = A(MxK) * B(NxK)^T ----------------
// MODE 0: xi-GEMM. A=x_bf16 (row m = b*S+s), epilogue v+bi[gn]+bh[gn],
//         store bf16 to xi laid out (S,B,H): row (s*B+b).
// MODE 1: out-GEMM. A=hs slots 1..S (row m = t*B+b), epilogue v+bo[gn],
//         store fp32 to out laid out (B,S,O): [(b*S+t)*O+gn].
template <int MODE>
__global__ __launch_bounds__(256) void k_gemm(
    const unsigned short* __restrict__ A, const unsigned short* __restrict__ Bm,
    const float* __restrict__ bias1, const float* __restrict__ bias2,
    void* __restrict__ Cout, int M, int N, int K)
{
    __shared__ unsigned short As[128][40];   // +8 pad: minimal bank conflicts
    __shared__ unsigned short Bs[128][40];

    const int tid  = threadIdx.x;
    const int m0   = blockIdx.x * 128;
    const int n0   = blockIdx.y * 128;
    const int wave = tid >> 6, lane = tid & 63;
    const int wm   = (wave >> 1) * 64, wn = (wave & 1) * 64;
    const int l16  = lane & 15, q = lane >> 4;

    f32x4 acc[4][4];
#pragma unroll
    for (int a = 0; a < 4; ++a)
#pragma unroll
        for (int b = 0; b < 4; ++b)
            acc[a][b] = (f32x4){0.f, 0.f, 0.f, 0.f};

    for (int k0 = 0; k0 < K; k0 += 32) {
        // stage 128x32 A-tile and B-tile (each: 512 chunks of 8 bf16, 2 per thread)
#pragma unroll
        for (int c = 0; c < 2; ++c) {
            int idx = tid + c * 256;
            int row = idx >> 2, col = (idx & 3) * 8;
            *(bf16x8*)&As[row][col] = *(const bf16x8*)&A [(m0 + row) * K + k0 + col];
            *(bf16x8*)&Bs[row][col] = *(const bf16x8*)&Bm[(n0 + row) * K + k0 + col];
        }
        __syncthreads();

        bf16x8 af[4], bfr[4];
#pragma unroll
        for (int mt = 0; mt < 4; ++mt) af[mt]  = *(const bf16x8*)&As[wm + mt * 16 + l16][q * 8];
#pragma unroll
        for (int nt = 0; nt < 4; ++nt) bfr[nt] = *(const bf16x8*)&Bs[wn + nt * 16 + l16][q * 8];
#pragma unroll
        for (int mt = 0; mt < 4; ++mt)
#pragma unroll
            for (int nt = 0; nt < 4; ++nt)
                acc[mt][nt] = __builtin_amdgcn_mfma_f32_16x16x32_bf16(af[mt], bfr[nt], acc[mt][nt], 0, 0, 0);
        __syncthreads();
    }

    // epilogue; C/D layout: col = lane&15, row = (lane>>4)*4 + reg
#pragma unroll
    for (int mt = 0; mt < 4; ++mt) {
#pragma unroll
        for (int nt = 0; nt < 4; ++nt) {
            int gn = n0 + wn + nt * 16 + l16;
#pragma unroll
            for (int i = 0; i < 4; ++i) {
                int gm = m0 + wm + mt * 16 + q * 4 + i;
                float v = acc[mt][nt][i];
                if (MODE == 0) {
                    v += bias1[gn] + bias2[gn];
                    int bb = gm >> 9, s = gm & (S_ - 1);       // gm = b*S+s
                    ((unsigned short*)Cout)[(s * B_ + bb) * H_ + gn] = f2bf(v);
                } else {
                    v += bias1[gn];
                    int t = gm >> 6, bb = gm & (B_ - 1);        // gm = t*B+b
                    ((float*)Cout)[((bb << 9) + t) * O_ + gn] = v;
                }
            }
        }
    }
}

// ---------------- sequential scan: h_{t+1} = tanh(xi_t + h_t * Wh^T) ----------------
// 64 blocks, block nb owns H-columns [nb*16, nb*16+16). Wh slice lives in LDS all scan.
// hs has S+1 slots; step t reads slot t, writes slot t+1. ctr[t] counts finished blocks.
__global__ __launch_bounds__(256) void k_scan(
    const unsigned short* __restrict__ xi,   // (S,B,H) bf16
    const unsigned short* __restrict__ Wh,   // (H,H) bf16, row = out idx, k-contiguous
    unsigned short* __restrict__ hs,         // (S+1,B,H) bf16
    int* __restrict__ ctr)                   // S ints, pre-zeroed
{
    __shared__ unsigned short Ws[16][1032];  // +8 pad
    const int nb  = blockIdx.x;
    const int n0  = nb * 16;
    const int tid = threadIdx.x;
    const int wave = tid >> 6, lane = tid & 63;
    const int l16 = lane & 15, q = lane >> 4;

    // stage Wh rows n0..n0+15 (16 x 1024 bf16 = 2048 chunks of 8, 8 per thread)
    for (int c = tid; c < 2048; c += 256) {
        int row = c >> 7, col = (c & 127) * 8;
        *(bf16x8*)&Ws[row][col] = *(const bf16x8*)&Wh[(n0 + row) * H_ + col];
    }
    __syncthreads();

    const int mrow = wave * 16 + l16;        // batch row this lane's A-frag covers

    for (int t = 0; t < S_; ++t) {
        if (t > 0) {
            if (tid == 0) {
                while (__hip_atomic_load(&ctr[t - 1], __ATOMIC_ACQUIRE,
                                         __HIP_MEMORY_SCOPE_AGENT) < 64) {}
            }
            __syncthreads();  // all threads' subsequent loads ordered after tid0's acquire
        }
        const unsigned short* hsrc = hs + t * HB;
        f32x4 acc = (f32x4){0.f, 0.f, 0.f, 0.f};
#pragma unroll 8
        for (int ks = 0; ks < 32; ++ks) {
            bf16x8 a = *(const bf16x8*)&hsrc[mrow * H_ + ks * 32 + q * 8];
            bf16x8 b = *(const bf16x8*)&Ws[l16][ks * 32 + q * 8];
            acc = __builtin_amdgcn_mfma_f32_16x16x32_bf16(a, b, acc, 0, 0, 0);
        }
        unsigned short* hdst = hs + (t + 1) * HB;
        const unsigned short* xit = xi + t * HB;
#pragma unroll
        for (int i = 0; i < 4; ++i) {
            int brow = wave * 16 + q * 4 + i;
            float v = acc[i] + bf2f(xit[brow * H_ + n0 + l16]);
            hdst[brow * H_ + n0 + l16] = f2bf(tanhf(v));
        }
        __syncthreads();  // drain this block's stores (emits vmcnt(0)) before flag
        if (tid == 0)
            __hip_atomic_fetch_add(&ctr[t], 1, __ATOMIC_RELEASE, __HIP_MEMORY_SCOPE_AGENT);
    }
}

// ---------------- h_last: hs slot S -> fp32 ----------------
__global__ void k_hlast(const unsigned short* __restrict__ hsS, float* __restrict__ out) {
    int i = blockIdx.x * blockDim.x + threadIdx.x;
    if (i < HB) out[i] = bf2f(hsS[i]);
}

extern "C" void kernel_launch(void* const* d_in, const int* in_sizes, int n_in,
                              void* d_out, int out_size, void* d_ws, size_t ws_size,
                              hipStream_t stream) {
    const float* x  = (const float*)d_in[0];
    const float* Wi = (const float*)d_in[1];
    const float* bi = (const float*)d_in[2];
    const float* Wh = (const float*)d_in[3];
    const float* bh = (const float*)d_in[4];
    const float* Wo = (const float*)d_in[5];
    const float* bo = (const float*)d_in[6];
    float* out = (float*)d_out;

    char* p = (char*)d_ws;
    unsigned short* x_bf  = (unsigned short*)p; p += (size_t)B_ * S_ * I_ * 2;   // 33.5 MB
    unsigned short* Wi_bf = (unsigned short*)p; p += (size_t)H_ * I_ * 2;        // 1 MB
    unsigned short* Wh_bf = (unsigned short*)p; p += (size_t)H_ * H_ * 2;        // 2 MB
    unsigned short* Wo_bf = (unsigned short*)p; p += (size_t)O_ * H_ * 2;        // 1 MB
    unsigned short* xi    = (unsigned short*)p; p += (size_t)S_ * B_ * H_ * 2;   // 67 MB
    unsigned short* hs    = (unsigned short*)p; p += (size_t)(S_ + 1) * HB * 2;  // 67 MB
    int* ctr = (int*)p;                                                          // 2 KB

    int n4;
    n4 = B_ * S_ * I_ / 4;
    k_f2bf4<<<(n4 + 255) / 256, 256, 0, stream>>>((const float4*)x,  (ushort4*)x_bf,  n4);
    n4 = H_ * I_ / 4;
    k_f2bf4<<<(n4 + 255) / 256, 256, 0, stream>>>((const float4*)Wi, (ushort4*)Wi_bf, n4);
    n4 = H_ * H_ / 4;
    k_f2bf4<<<(n4 + 255) / 256, 256, 0, stream>>>((const float4*)Wh, (ushort4*)Wh_bf, n4);
    n4 = O_ * H_ / 4;
    k_f2bf4<<<(n4 + 255) / 256, 256, 0, stream>>>((const float4*)Wo, (ushort4*)Wo_bf, n4);
    k_init<<<256, 256, 0, stream>>>(hs, ctr);

    // xi = x * Wi^T + bi + bh   (M=32768, N=1024, K=512)
    k_gemm<0><<<dim3(B_ * S_ / 128, H_ / 128), 256, 0, stream>>>(
        x_bf, Wi_bf, bi, bh, (void*)xi, B_ * S_, H_, I_);

    // sequential scan
    k_scan<<<64, 256, 0, stream>>>(xi, Wh_bf, hs, ctr);

    // out = hs * Wo^T + bo      (M=32768, N=512, K=1024)
    k_gemm<1><<<dim3(B_ * S_ / 128, O_ / 128), 256, 0, stream>>>(
        hs + HB, Wo_bf, bo, nullptr, (void*)out, B_ * S_, O_, H_);

    // h_last
    k_hlast<<<(HB + 255) / 256, 256, 0, stream>>>(hs + (size_t)S_ * HB, out + (size_t)B_ * S_ * O_);
}

// Round 2
// 4597.960 us; speedup vs baseline: 1.0643x; 1.0643x over previous
//
#include <hip/hip_runtime.h>
#include <stdint.h>

#define B_ 64
#define S_ 512
#define I_ 512
#define H_ 1024
#define O_ 512
#define HB (B_ * H_)   // 65536 elements per hs slot

typedef __attribute__((ext_vector_type(8))) short bf16x8;   // 8 bf16 in 4 VGPRs
typedef __attribute__((ext_vector_type(4))) float f32x4;

__device__ inline unsigned short f2bf(float f) {
    union { float f; unsigned u; } v; v.f = f;
    unsigned r = v.u + 0x7fffu + ((v.u >> 16) & 1u);   // RNE
    return (unsigned short)(r >> 16);
}
__device__ inline float bf2f(unsigned short h) {
    union { unsigned u; float f; } v; v.u = ((unsigned)h) << 16; return v.f;
}

// ---------------- fp32 -> bf16 convert (x4 vectorized) ----------------
__global__ void k_f2bf4(const float4* __restrict__ src, ushort4* __restrict__ dst, int n4) {
    int i = blockIdx.x * blockDim.x + threadIdx.x;
    if (i < n4) {
        float4 v = src[i];
        ushort4 o;
        o.x = f2bf(v.x); o.y = f2bf(v.y); o.z = f2bf(v.z); o.w = f2bf(v.w);
        dst[i] = o;
    }
}

// ---------------- init: hs slot 0 = 0 (h0), flags = 0 ----------------
#define NFLAGS (4 * S_ * 16)
__global__ void k_init(unsigned short* __restrict__ hs0, int* __restrict__ flags) {
    int i = blockIdx.x * blockDim.x + threadIdx.x;
    if (i < HB) hs0[i] = 0;
    if (i < NFLAGS) flags[i] = 0;
}

// ---------------- generic 128x128 bf16 MFMA GEMM: C = A(MxK) * B(NxK)^T ----------------
// MODE 0: xi-GEMM. A=x_bf16 (row m = b*S+s), epilogue v+bi[gn]+bh[gn],
//         store bf16 to xi laid out (S,B,H): row (s*B+b).
// MODE 1: out-GEMM. A=hs slots 1..S (row m = t*B+b), epilogue v+bo[gn],
//         store fp32 to out laid out (B,S,O): [(b*S+t)*O+gn].
template <int MODE>
__global__ __launch_bounds__(256) void k_gemm(
    const unsigned short* __restrict__ A, const unsigned short* __restrict__ Bm,
    const float* __restrict__ bias1, const float* __restrict__ bias2,
    void* __restrict__ Cout, int M, int N, int K)
{
    __shared__ unsigned short As[128][40];   // +8 pad: minimal bank conflicts
    __shared__ unsigned short Bs[128][40];

    const int tid  = threadIdx.x;
    const int m0   = blockIdx.x * 128;
    const int n0   = blockIdx.y * 128;
    const int wave = tid >> 6, lane = tid & 63;
    const int wm   = (wave >> 1) * 64, wn = (wave & 1) * 64;
    const int l16  = lane & 15, q = lane >> 4;

    f32x4 acc[4][4];
#pragma unroll
    for (int a = 0; a < 4; ++a)
#pragma unroll
        for (int b = 0; b < 4; ++b)
            acc[a][b] = (f32x4){0.f, 0.f, 0.f, 0.f};

    for (int k0 = 0; k0 < K; k0 += 32) {
#pragma unroll
        for (int c = 0; c < 2; ++c) {
            int idx = tid + c * 256;
            int row = idx >> 2, col = (idx & 3) * 8;
            *(bf16x8*)&As[row][col] = *(const bf16x8*)&A [(m0 + row) * K + k0 + col];
            *(bf16x8*)&Bs[row][col] = *(const bf16x8*)&Bm[(n0 + row) * K + k0 + col];
        }
        __syncthreads();

        bf16x8 af[4], bfr[4];
#pragma unroll
        for (int mt = 0; mt < 4; ++mt) af[mt]  = *(const bf16x8*)&As[wm + mt * 16 + l16][q * 8];
#pragma unroll
        for (int nt = 0; nt < 4; ++nt) bfr[nt] = *(const bf16x8*)&Bs[wn + nt * 16 + l16][q * 8];
#pragma unroll
        for (int mt = 0; mt < 4; ++mt)
#pragma unroll
            for (int nt = 0; nt < 4; ++nt)
                acc[mt][nt] = __builtin_amdgcn_mfma_f32_16x16x32_bf16(af[mt], bfr[nt], acc[mt][nt], 0, 0, 0);
        __syncthreads();
    }

    // epilogue; C/D layout: col = lane&15, row = (lane>>4)*4 + reg
#pragma unroll
    for (int mt = 0; mt < 4; ++mt) {
#pragma unroll
        for (int nt = 0; nt < 4; ++nt) {
            int gn = n0 + wn + nt * 16 + l16;
#pragma unroll
            for (int i = 0; i < 4; ++i) {
                int gm = m0 + wm + mt * 16 + q * 4 + i;
                float v = acc[mt][nt][i];
                if (MODE == 0) {
                    v += bias1[gn] + bias2[gn];
                    int bb = gm >> 9, s = gm & (S_ - 1);       // gm = b*S+s
                    ((unsigned short*)Cout)[(s * B_ + bb) * H_ + gn] = f2bf(v);
                } else {
                    v += bias1[gn];
                    int t = gm >> 6, bb = gm & (B_ - 1);        // gm = t*B+b
                    ((float*)Cout)[((bb << 9) + t) * O_ + gn] = v;
                }
            }
        }
    }
}

// ---------------- sequential scan: h_{t+1} = tanh(xi_t + h_t * Wh^T) ----------------
// Batch is independent across rows -> 4 batch-groups of 16 rows; each group has 16
// col-blocks owning 64 H-columns. Sync only within a group (degree 16), via per-producer
// flag words: RELAXED polling + ONE acquire fence per step (no per-poll L2 invalidate).
// Wh slice (64x1024 bf16, pitch 1032) lives in dynamic LDS for the whole scan.
__global__ __launch_bounds__(256) void k_scan(
    const unsigned short* __restrict__ xi,   // (S,B,H) bf16
    const unsigned short* __restrict__ Wh,   // (H,H) bf16, row = out idx, k-contiguous
    unsigned short* __restrict__ hs,         // (S+1,B,H) bf16
    int* __restrict__ flags)                 // (4,S,16) ints, pre-zeroed
{
    extern __shared__ unsigned short Ws[];   // [64][1032]  = 132096 B
    const int bid = blockIdx.x;
    const int g   = bid & 3;                 // batch group: rows 16g..16g+15
    const int j   = bid >> 2;                // col block:   cols 64j..64j+63
    const int n0  = j * 64;
    const int r0  = g * 16;
    const int tid = threadIdx.x;
    const int wave = tid >> 6, lane = tid & 63;
    const int l16 = lane & 15, q = lane >> 4;

    // stage Wh rows n0..n0+63 (8192 chunks of 8 bf16, 32 per thread)
    for (int c = tid; c < 8192; c += 256) {
        int row = c >> 7, col = (c & 127) * 8;
        *(bf16x8*)&Ws[row * 1032 + col] = *(const bf16x8*)&Wh[(n0 + row) * H_ + col];
    }
    __syncthreads();

    const int fbase = g * S_ * 16;
    const unsigned short* wrow = &Ws[(wave * 16 + l16) * 1032];

    for (int t = 0; t < S_; ++t) {
        if (t > 0) {
            if (q == 0) {   // lanes 0..15 of every wave each poll one producer flag
                const int* f = &flags[fbase + (t - 1) * 16 + l16];
                while (__hip_atomic_load(f, __ATOMIC_RELAXED,
                                         __HIP_MEMORY_SCOPE_AGENT) == 0) {}
            }
            __builtin_amdgcn_fence(__ATOMIC_ACQUIRE, "agent");  // one L2 inv per step
        }
        const unsigned short* hsrc = hs + (size_t)t * HB + (size_t)r0 * H_;
        f32x4 acc0 = (f32x4){0.f, 0.f, 0.f, 0.f};
        f32x4 acc1 = (f32x4){0.f, 0.f, 0.f, 0.f};
#pragma unroll
        for (int ks = 0; ks < 32; ks += 2) {
            bf16x8 a0 = *(const bf16x8*)&hsrc[l16 * H_ + ks * 32 + q * 8];
            bf16x8 b0 = *(const bf16x8*)&wrow[ks * 32 + q * 8];
            acc0 = __builtin_amdgcn_mfma_f32_16x16x32_bf16(a0, b0, acc0, 0, 0, 0);
            bf16x8 a1 = *(const bf16x8*)&hsrc[l16 * H_ + (ks + 1) * 32 + q * 8];
            bf16x8 b1 = *(const bf16x8*)&wrow[(ks + 1) * 32 + q * 8];
            acc1 = __builtin_amdgcn_mfma_f32_16x16x32_bf16(a1, b1, acc1, 0, 0, 0);
        }
        unsigned short* hdst = hs + (size_t)(t + 1) * HB;
        const unsigned short* xit = xi + (size_t)t * HB;
        const int ncol = n0 + wave * 16 + l16;
#pragma unroll
        for (int i = 0; i < 4; ++i) {
            int r = r0 + q * 4 + i;
            float v = acc0[i] + acc1[i] + bf2f(xit[r * H_ + ncol]);
            hdst[r * H_ + ncol] = f2bf(tanhf(v));
        }
        __syncthreads();   // drains all waves' stores to L2 (vmcnt0 before barrier)
        if (tid == 0) {
            __builtin_amdgcn_fence(__ATOMIC_RELEASE, "agent");  // wbl2: make them visible
            __hip_atomic_store(&flags[fbase + t * 16 + j], 1,
                               __ATOMIC_RELAXED, __HIP_MEMORY_SCOPE_AGENT);
        }
    }
}

// ---------------- h_last: hs slot S -> fp32 ----------------
__global__ void k_hlast(const unsigned short* __restrict__ hsS, float* __restrict__ out) {
    int i = blockIdx.x * blockDim.x + threadIdx.x;
    if (i < HB) out[i] = bf2f(hsS[i]);
}

extern "C" void kernel_launch(void* const* d_in, const int* in_sizes, int n_in,
                              void* d_out, int out_size, void* d_ws, size_t ws_size,
                              hipStream_t stream) {
    const float* x  = (const float*)d_in[0];
    const float* Wi = (const float*)d_in[1];
    const float* bi = (const float*)d_in[2];
    const float* Wh = (const float*)d_in[3];
    const float* bh = (const float*)d_in[4];
    const float* Wo = (const float*)d_in[5];
    const float* bo = (const float*)d_in[6];
    float* out = (float*)d_out;

    char* p = (char*)d_ws;
    unsigned short* x_bf  = (unsigned short*)p; p += (size_t)B_ * S_ * I_ * 2;   // 33.5 MB
    unsigned short* Wi_bf = (unsigned short*)p; p += (size_t)H_ * I_ * 2;        // 1 MB
    unsigned short* Wh_bf = (unsigned short*)p; p += (size_t)H_ * H_ * 2;        // 2 MB
    unsigned short* Wo_bf = (unsigned short*)p; p += (size_t)O_ * H_ * 2;        // 1 MB
    unsigned short* xi    = (unsigned short*)p; p += (size_t)S_ * B_ * H_ * 2;   // 67 MB
    unsigned short* hs    = (unsigned short*)p; p += (size_t)(S_ + 1) * HB * 2;  // 67 MB
    int* flags = (int*)p;                                                        // 128 KB

    int n4;
    n4 = B_ * S_ * I_ / 4;
    k_f2bf4<<<(n4 + 255) / 256, 256, 0, stream>>>((const float4*)x,  (ushort4*)x_bf,  n4);
    n4 = H_ * I_ / 4;
    k_f2bf4<<<(n4 + 255) / 256, 256, 0, stream>>>((const float4*)Wi, (ushort4*)Wi_bf, n4);
    n4 = H_ * H_ / 4;
    k_f2bf4<<<(n4 + 255) / 256, 256, 0, stream>>>((const float4*)Wh, (ushort4*)Wh_bf, n4);
    n4 = O_ * H_ / 4;
    k_f2bf4<<<(n4 + 255) / 256, 256, 0, stream>>>((const float4*)Wo, (ushort4*)Wo_bf, n4);
    k_init<<<256, 256, 0, stream>>>(hs, flags);

    // xi = x * Wi^T + bi + bh   (M=32768, N=1024, K=512)
    k_gemm<0><<<dim3(B_ * S_ / 128, H_ / 128), 256, 0, stream>>>(
        x_bf, Wi_bf, bi, bh, (void*)xi, B_ * S_, H_, I_);

    // sequential scan: 64 blocks = 4 batch-groups x 16 col-blocks, 132 KB dynamic LDS
    (void)hipFuncSetAttribute((const void*)k_scan,
                              hipFuncAttributeMaxDynamicSharedMemorySize, 64 * 1032 * 2);
    k_scan<<<64, 256, 64 * 1032 * 2, stream>>>(xi, Wh_bf, hs, flags);

    // out = hs * Wo^T + bo      (M=32768, N=512, K=1024)
    k_gemm<1><<<dim3(B_ * S_ / 128, O_ / 128), 256, 0, stream>>>(
        hs + HB, Wo_bf, bo, nullptr, (void*)out, B_ * S_, O_, H_);

    // h_last
    k_hlast<<<(HB + 255) / 256, 256, 0, stream>>>(hs + (size_t)S_ * HB, out + (size_t)B_ * S_ * O_);
}

// Round 3
// 4534.041 us; speedup vs baseline: 1.0793x; 1.0141x over previous
//
#include <hip/hip_runtime.h>
#include <stdint.h>

#define B_ 64
#define S_ 512
#define I_ 512
#define H_ 1024
#define O_ 512
#define HB (B_ * H_)   // 65536 elements per hs slot

typedef __attribute__((ext_vector_type(8))) short bf16x8;   // 8 bf16 in 4 VGPRs
typedef __attribute__((ext_vector_type(4))) float f32x4;
typedef unsigned long long u64;

__device__ inline unsigned short f2bf(float f) {
    union { float f; unsigned u; } v; v.f = f;
    unsigned r = v.u + 0x7fffu + ((v.u >> 16) & 1u);   // RNE
    return (unsigned short)(r >> 16);
}
__device__ inline float bf2f(unsigned short h) {
    union { unsigned u; float f; } v; v.u = ((unsigned)h) << 16; return v.f;
}

// ---------------- fp32 -> bf16 convert (x4 vectorized) ----------------
__global__ void k_f2bf4(const float4* __restrict__ src, ushort4* __restrict__ dst, int n4) {
    int i = blockIdx.x * blockDim.x + threadIdx.x;
    if (i < n4) {
        float4 v = src[i];
        ushort4 o;
        o.x = f2bf(v.x); o.y = f2bf(v.y); o.z = f2bf(v.z); o.w = f2bf(v.w);
        dst[i] = o;
    }
}

// ---------------- init: hs slot 0 = 0 (h0), flags = 0 ----------------
#define NFLAGS (4 * S_ * 16)
__global__ void k_init(unsigned short* __restrict__ hs0, int* __restrict__ flags) {
    int i = blockIdx.x * blockDim.x + threadIdx.x;
    if (i < HB) hs0[i] = 0;
    if (i < NFLAGS) flags[i] = 0;
}

// ---------------- generic 128x128 bf16 MFMA GEMM: C = A(MxK) * B(NxK)^T ----------------
template <int MODE>
__global__ __launch_bounds__(256) void k_gemm(
    const unsigned short* __restrict__ A, const unsigned short* __restrict__ Bm,
    const float* __restrict__ bias1, const float* __restrict__ bias2,
    void* __restrict__ Cout, int M, int N, int K)
{
    __shared__ unsigned short As[128][40];
    __shared__ unsigned short Bs[128][40];

    const int tid  = threadIdx.x;
    const int m0   = blockIdx.x * 128;
    const int n0   = blockIdx.y * 128;
    const int wave = tid >> 6, lane = tid & 63;
    const int wm   = (wave >> 1) * 64, wn = (wave & 1) * 64;
    const int l16  = lane & 15, q = lane >> 4;

    f32x4 acc[4][4];
#pragma unroll
    for (int a = 0; a < 4; ++a)
#pragma unroll
        for (int b = 0; b < 4; ++b)
            acc[a][b] = (f32x4){0.f, 0.f, 0.f, 0.f};

    for (int k0 = 0; k0 < K; k0 += 32) {
#pragma unroll
        for (int c = 0; c < 2; ++c) {
            int idx = tid + c * 256;
            int row = idx >> 2, col = (idx & 3) * 8;
            *(bf16x8*)&As[row][col] = *(const bf16x8*)&A [(m0 + row) * K + k0 + col];
            *(bf16x8*)&Bs[row][col] = *(const bf16x8*)&Bm[(n0 + row) * K + k0 + col];
        }
        __syncthreads();

        bf16x8 af[4], bfr[4];
#pragma unroll
        for (int mt = 0; mt < 4; ++mt) af[mt]  = *(const bf16x8*)&As[wm + mt * 16 + l16][q * 8];
#pragma unroll
        for (int nt = 0; nt < 4; ++nt) bfr[nt] = *(const bf16x8*)&Bs[wn + nt * 16 + l16][q * 8];
#pragma unroll
        for (int mt = 0; mt < 4; ++mt)
#pragma unroll
            for (int nt = 0; nt < 4; ++nt)
                acc[mt][nt] = __builtin_amdgcn_mfma_f32_16x16x32_bf16(af[mt], bfr[nt], acc[mt][nt], 0, 0, 0);
        __syncthreads();
    }

    // epilogue; C/D layout: col = lane&15, row = (lane>>4)*4 + reg
#pragma unroll
    for (int mt = 0; mt < 4; ++mt) {
#pragma unroll
        for (int nt = 0; nt < 4; ++nt) {
            int gn = n0 + wn + nt * 16 + l16;
#pragma unroll
            for (int i = 0; i < 4; ++i) {
                int gm = m0 + wm + mt * 16 + q * 4 + i;
                float v = acc[mt][nt][i];
                if (MODE == 0) {
                    v += bias1[gn] + bias2[gn];
                    int bb = gm >> 9, s = gm & (S_ - 1);       // gm = b*S+s
                    ((unsigned short*)Cout)[(s * B_ + bb) * H_ + gn] = f2bf(v);
                } else {
                    v += bias1[gn];
                    int t = gm >> 6, bb = gm & (B_ - 1);        // gm = t*B+b
                    ((float*)Cout)[((bb << 9) + t) * O_ + gn] = v;
                }
            }
        }
    }
}

// ---------------- sequential scan: h_{t+1} = tanh(xi_t + h_t * Wh^T) ----------------
// 4 batch-groups x 16 col-blocks. NO cache-wide fences anywhere: h traffic uses
// relaxed AGENT-scope atomic loads/stores (per-instruction sc-bit coherence,
// write-through / read-through at the coherence point). Producer ordering comes from
// __syncthreads' vmcnt(0) drain; consumer ordering from the poll branch dependency.
__global__ __launch_bounds__(256) void k_scan(
    const unsigned short* __restrict__ xi,   // (S,B,H) bf16
    const unsigned short* __restrict__ Wh,   // (H,H) bf16
    unsigned short* __restrict__ hs,         // (S+1,B,H) bf16
    int* __restrict__ flags)                 // (4,S,16) ints, pre-zeroed
{
    extern __shared__ unsigned short Ws[];   // [64][1032] = 132096 B
    const int bid = blockIdx.x;
    const int g   = bid & 3;                 // batch group: rows 16g..16g+15
    const int j   = bid >> 2;                // col block:   cols 64j..64j+63
    const int n0  = j * 64;
    const int r0  = g * 16;
    const int tid = threadIdx.x;
    const int wave = tid >> 6, lane = tid & 63;
    const int l16 = lane & 15, q = lane >> 4;

    for (int c = tid; c < 8192; c += 256) {
        int row = c >> 7, col = (c & 127) * 8;
        *(bf16x8*)&Ws[row * 1032 + col] = *(const bf16x8*)&Wh[(n0 + row) * H_ + col];
    }
    __syncthreads();

    const int fbase = g * S_ * 16;
    const unsigned short* wrow = &Ws[(wave * 16 + l16) * 1032];
    const int ncol = n0 + wave * 16 + l16;

    union HU { u64 qw[2]; bf16x8 v; };

    for (int t = 0; t < S_; ++t) {
        // xi prefetch: independent of h, issued before the poll so latency overlaps waiting
        const unsigned short* xit = xi + (size_t)t * HB;
        float xiv[4];
#pragma unroll
        for (int i = 0; i < 4; ++i)
            xiv[i] = bf2f(xit[(r0 + q * 4 + i) * H_ + ncol]);

        if (t > 0) {
            if (q == 0) {   // lanes 0..15 of each wave poll one producer flag each
                const int* f = &flags[fbase + (t - 1) * 16 + l16];
                while (__hip_atomic_load(f, __ATOMIC_RELAXED,
                                         __HIP_MEMORY_SCOPE_AGENT) == 0) {}
            }
            asm volatile("" ::: "memory");   // compiler barrier only — no cache ops
        }

        // h loads: relaxed agent atomics (sc-bypass), issued 16 iters ahead -> pipelined
        const u64* hp = (const u64*)(hs + (size_t)t * HB + (size_t)(r0 + l16) * H_);
        f32x4 acc0 = (f32x4){0.f, 0.f, 0.f, 0.f};
        f32x4 acc1 = (f32x4){0.f, 0.f, 0.f, 0.f};
#pragma unroll
        for (int c = 0; c < 2; ++c) {
            u64 hbuf[16][2];
#pragma unroll
            for (int i = 0; i < 16; ++i) {
                int ks = c * 16 + i;
                hbuf[i][0] = __hip_atomic_load(hp + ks * 8 + q * 2,     __ATOMIC_RELAXED, __HIP_MEMORY_SCOPE_AGENT);
                hbuf[i][1] = __hip_atomic_load(hp + ks * 8 + q * 2 + 1, __ATOMIC_RELAXED, __HIP_MEMORY_SCOPE_AGENT);
            }
#pragma unroll
            for (int i = 0; i < 16; ++i) {
                int ks = c * 16 + i;
                HU a; a.qw[0] = hbuf[i][0]; a.qw[1] = hbuf[i][1];
                bf16x8 b = *(const bf16x8*)&wrow[ks * 32 + q * 8];
                if (i & 1) acc1 = __builtin_amdgcn_mfma_f32_16x16x32_bf16(a.v, b, acc1, 0, 0, 0);
                else       acc0 = __builtin_amdgcn_mfma_f32_16x16x32_bf16(a.v, b, acc0, 0, 0, 0);
            }
        }

        unsigned short* hdst = hs + (size_t)(t + 1) * HB;
#pragma unroll
        for (int i = 0; i < 4; ++i) {
            int r = r0 + q * 4 + i;
            unsigned short hv = f2bf(tanhf(acc0[i] + acc1[i] + xiv[i]));
            __hip_atomic_store(&hdst[r * H_ + ncol], hv,
                               __ATOMIC_RELAXED, __HIP_MEMORY_SCOPE_AGENT);  // write-through
        }
        __syncthreads();   // compiler emits s_waitcnt vmcnt(0) before s_barrier -> stores visible
        if (tid == 0)
            __hip_atomic_store(&flags[fbase + t * 16 + j], 1,
                               __ATOMIC_RELAXED, __HIP_MEMORY_SCOPE_AGENT);
    }
}

// ---------------- h_last: hs slot S -> fp32 ----------------
__global__ void k_hlast(const unsigned short* __restrict__ hsS, float* __restrict__ out) {
    int i = blockIdx.x * blockDim.x + threadIdx.x;
    if (i < HB) out[i] = bf2f(hsS[i]);
}

extern "C" void kernel_launch(void* const* d_in, const int* in_sizes, int n_in,
                              void* d_out, int out_size, void* d_ws, size_t ws_size,
                              hipStream_t stream) {
    const float* x  = (const float*)d_in[0];
    const float* Wi = (const float*)d_in[1];
    const float* bi = (const float*)d_in[2];
    const float* Wh = (const float*)d_in[3];
    const float* bh = (const float*)d_in[4];
    const float* Wo = (const float*)d_in[5];
    const float* bo = (const float*)d_in[6];
    float* out = (float*)d_out;

    char* p = (char*)d_ws;
    unsigned short* x_bf  = (unsigned short*)p; p += (size_t)B_ * S_ * I_ * 2;
    unsigned short* Wi_bf = (unsigned short*)p; p += (size_t)H_ * I_ * 2;
    unsigned short* Wh_bf = (unsigned short*)p; p += (size_t)H_ * H_ * 2;
    unsigned short* Wo_bf = (unsigned short*)p; p += (size_t)O_ * H_ * 2;
    unsigned short* xi    = (unsigned short*)p; p += (size_t)S_ * B_ * H_ * 2;
    unsigned short* hs    = (unsigned short*)p; p += (size_t)(S_ + 1) * HB * 2;
    int* flags = (int*)p;

    int n4;
    n4 = B_ * S_ * I_ / 4;
    k_f2bf4<<<(n4 + 255) / 256, 256, 0, stream>>>((const float4*)x,  (ushort4*)x_bf,  n4);
    n4 = H_ * I_ / 4;
    k_f2bf4<<<(n4 + 255) / 256, 256, 0, stream>>>((const float4*)Wi, (ushort4*)Wi_bf, n4);
    n4 = H_ * H_ / 4;
    k_f2bf4<<<(n4 + 255) / 256, 256, 0, stream>>>((const float4*)Wh, (ushort4*)Wh_bf, n4);
    n4 = O_ * H_ / 4;
    k_f2bf4<<<(n4 + 255) / 256, 256, 0, stream>>>((const float4*)Wo, (ushort4*)Wo_bf, n4);
    k_init<<<256, 256, 0, stream>>>(hs, flags);

    // xi = x * Wi^T + bi + bh   (M=32768, N=1024, K=512)
    k_gemm<0><<<dim3(B_ * S_ / 128, H_ / 128), 256, 0, stream>>>(
        x_bf, Wi_bf, bi, bh, (void*)xi, B_ * S_, H_, I_);

    // sequential scan: 64 blocks = 4 batch-groups x 16 col-blocks, 132 KB dynamic LDS
    (void)hipFuncSetAttribute((const void*)k_scan,
                              hipFuncAttributeMaxDynamicSharedMemorySize, 64 * 1032 * 2);
    k_scan<<<64, 256, 64 * 1032 * 2, stream>>>(xi, Wh_bf, hs, flags);

    // out = hs * Wo^T + bo      (M=32768, N=512, K=1024)
    k_gemm<1><<<dim3(B_ * S_ / 128, O_ / 128), 256, 0, stream>>>(
        hs + HB, Wo_bf, bo, nullptr, (void*)out, B_ * S_, O_, H_);

    // h_last
    k_hlast<<<(HB + 255) / 256, 256, 0, stream>>>(hs + (size_t)S_ * HB, out + (size_t)B_ * S_ * O_);
}

// Round 4
// 2316.609 us; speedup vs baseline: 2.1125x; 1.9572x over previous
//
#include <hip/hip_runtime.h>
#include <stdint.h>

#define B_ 64
#define S_ 512
#define I_ 512
#define H_ 1024
#define O_ 512
#define HB (B_ * H_)   // 65536 elements per hs slot
#define PRODS 64       // producers per batch-group = 16 blocks * 4 waves
#define NFLAGS (4 * S_ * PRODS)

typedef __attribute__((ext_vector_type(8))) short bf16x8;   // 8 bf16 in 4 VGPRs
typedef __attribute__((ext_vector_type(4))) float f32x4;
typedef unsigned long long u64;

__device__ inline unsigned short f2bf(float f) {
    union { float f; unsigned u; } v; v.f = f;
    unsigned r = v.u + 0x7fffu + ((v.u >> 16) & 1u);   // RNE
    return (unsigned short)(r >> 16);
}
__device__ inline float bf2f(unsigned short h) {
    union { unsigned u; float f; } v; v.u = ((unsigned)h) << 16; return v.f;
}

// ---------------- fp32 -> bf16 convert (x4 vectorized) ----------------
__global__ void k_f2bf4(const float4* __restrict__ src, ushort4* __restrict__ dst, int n4) {
    int i = blockIdx.x * blockDim.x + threadIdx.x;
    if (i < n4) {
        float4 v = src[i];
        ushort4 o;
        o.x = f2bf(v.x); o.y = f2bf(v.y); o.z = f2bf(v.z); o.w = f2bf(v.w);
        dst[i] = o;
    }
}

// ---------------- init: hs slot 0 = 0 (h0), flags = 0 ----------------
__global__ void k_init(unsigned short* __restrict__ hs0, int* __restrict__ flags) {
    int i = blockIdx.x * blockDim.x + threadIdx.x;
    if (i < HB) hs0[i] = 0;
    if (i < NFLAGS) flags[i] = 0;
}

// ---------------- generic 128x128 bf16 MFMA GEMM: C = A(MxK) * B(NxK)^T ----------------
template <int MODE>
__global__ __launch_bounds__(256) void k_gemm(
    const unsigned short* __restrict__ A, const unsigned short* __restrict__ Bm,
    const float* __restrict__ bias1, const float* __restrict__ bias2,
    void* __restrict__ Cout, int M, int N, int K)
{
    __shared__ unsigned short As[128][40];
    __shared__ unsigned short Bs[128][40];

    const int tid  = threadIdx.x;
    const int m0   = blockIdx.x * 128;
    const int n0   = blockIdx.y * 128;
    const int wave = tid >> 6, lane = tid & 63;
    const int wm   = (wave >> 1) * 64, wn = (wave & 1) * 64;
    const int l16  = lane & 15, q = lane >> 4;

    f32x4 acc[4][4];
#pragma unroll
    for (int a = 0; a < 4; ++a)
#pragma unroll
        for (int b = 0; b < 4; ++b)
            acc[a][b] = (f32x4){0.f, 0.f, 0.f, 0.f};

    for (int k0 = 0; k0 < K; k0 += 32) {
#pragma unroll
        for (int c = 0; c < 2; ++c) {
            int idx = tid + c * 256;
            int row = idx >> 2, col = (idx & 3) * 8;
            *(bf16x8*)&As[row][col] = *(const bf16x8*)&A [(m0 + row) * K + k0 + col];
            *(bf16x8*)&Bs[row][col] = *(const bf16x8*)&Bm[(n0 + row) * K + k0 + col];
        }
        __syncthreads();

        bf16x8 af[4], bfr[4];
#pragma unroll
        for (int mt = 0; mt < 4; ++mt) af[mt]  = *(const bf16x8*)&As[wm + mt * 16 + l16][q * 8];
#pragma unroll
        for (int nt = 0; nt < 4; ++nt) bfr[nt] = *(const bf16x8*)&Bs[wn + nt * 16 + l16][q * 8];
#pragma unroll
        for (int mt = 0; mt < 4; ++mt)
#pragma unroll
            for (int nt = 0; nt < 4; ++nt)
                acc[mt][nt] = __builtin_amdgcn_mfma_f32_16x16x32_bf16(af[mt], bfr[nt], acc[mt][nt], 0, 0, 0);
        __syncthreads();
    }

    // epilogue; C/D layout: col = lane&15, row = (lane>>4)*4 + reg
#pragma unroll
    for (int mt = 0; mt < 4; ++mt) {
#pragma unroll
        for (int nt = 0; nt < 4; ++nt) {
            int gn = n0 + wn + nt * 16 + l16;
#pragma unroll
            for (int i = 0; i < 4; ++i) {
                int gm = m0 + wm + mt * 16 + q * 4 + i;
                float v = acc[mt][nt][i];
                if (MODE == 0) {
                    v += bias1[gn] + bias2[gn];
                    int bb = gm >> 9, s = gm & (S_ - 1);       // gm = b*S+s
                    ((unsigned short*)Cout)[(s * B_ + bb) * H_ + gn] = f2bf(v);
                } else {
                    v += bias1[gn];
                    int t = gm >> 6, bb = gm & (B_ - 1);        // gm = t*B+b
                    ((float*)Cout)[((bb << 9) + t) * O_ + gn] = v;
                }
            }
        }
    }
}

// ---------------- sequential scan: h_{t+1} = tanh(xi_t + h_t * Wh^T) ----------------
// 4 batch-groups x 16 col-blocks. Per step, ONE pipelined MALL read (8x asm
// global_load_dwordx4 sc0 sc1 per lane -> LDS), MFMA from LDS, asm short stores
// (sc0 sc1, no CAS), per-wave flags (no end-of-step barrier). XOR-swizzled LDS,
// Ws(128K) + hA(32K) = exactly 160 KiB.
__global__ __launch_bounds__(256, 1) void k_scan(
    const unsigned short* __restrict__ xi,   // (S,B,H) bf16
    const unsigned short* __restrict__ Wh,   // (H,H) bf16
    unsigned short* __restrict__ hs,         // (S+1,B,H) bf16
    int* __restrict__ flags)                 // (4,S,64) ints, pre-zeroed
{
    extern __shared__ char lds[];
    unsigned short* Ws = (unsigned short*)lds;                  // [64][1024] swizzled
    unsigned short* hA = (unsigned short*)(lds + 64 * 1024 * 2); // [16][1024] swizzled

    const int bid = blockIdx.x;
    const int g   = bid & 3;                 // batch group: rows 16g..16g+15
    const int j   = bid >> 2;                // col block:   cols 64j..64j+63
    const int n0  = j * 64;
    const int r0  = g * 16;
    const int tid = threadIdx.x;
    const int wave = tid >> 6, lane = tid & 63;
    const int l16 = lane & 15, q = lane >> 4;

    // stage Wh rows n0..n0+63, swizzled: chunk (row, cc) at cc^(row&7)
    for (int c = tid; c < 8192; c += 256) {
        int row = c >> 7, cc = c & 127;
        *(bf16x8*)&Ws[row * 1024 + ((cc ^ (row & 7)) * 8)] =
            *(const bf16x8*)&Wh[(n0 + row) * H_ + cc * 8];
    }
    __syncthreads();

    const int fbase = g * S_ * PRODS;
    const int brow  = wave * 16 + l16;       // Ws row for B-fragment
    const int ncol  = n0 + wave * 16 + l16;  // output column this lane owns
    const int pid   = j * 4 + wave;          // producer id (col-chunk of 16)

    for (int t = 0; t < S_; ++t) {
        // xi prefetch (plain cached loads; xi is written by a prior kernel, read-only)
        const unsigned short* xit = xi + (size_t)t * HB;
        float xiv[4];
#pragma unroll
        for (int i = 0; i < 4; ++i)
            xiv[i] = bf2f(xit[(r0 + q * 4 + i) * H_ + ncol]);

        if (t > 0) {
            // 64 lanes poll the 64 producer flags of step t-1 (all waves poll)
            const int* f = &flags[fbase + (t - 1) * PRODS + lane];
            for (;;) {
                int v = __hip_atomic_load(f, __ATOMIC_RELAXED, __HIP_MEMORY_SCOPE_AGENT);
                if (__ballot(v == 0) == 0ull) break;
            }
            asm volatile("" ::: "memory");
        }

        // cooperative h load: block reads the group's contiguous 32 KB slice once.
        // 8 coalesced b128 loads/lane, issued back-to-back (asm: compiler cannot sink).
        const char* hb = (const char*)(hs + (size_t)t * HB + (size_t)r0 * H_);
        float4 hv[8];
#pragma unroll
        for (int k = 0; k < 8; ++k) {
            const char* a = hb + ((size_t)(tid + k * 256) * 16);
            asm volatile("global_load_dwordx4 %0, %1, off sc0 sc1"
                         : "=v"(hv[k]) : "v"(a));
        }
        asm volatile("s_waitcnt vmcnt(0)" ::: "memory");
#pragma unroll
        for (int k = 0; k < 8; ++k) {
            int ci = tid + k * 256;
            int row = ci >> 7, cc = ci & 127;
            *(float4*)&hA[row * 1024 + ((cc ^ (row & 7)) * 8)] = hv[k];
        }
        __syncthreads();

        // 32 MFMAs: A-frag from hA (row l16), B-frag from Ws (row brow)
        f32x4 acc0 = (f32x4){0.f, 0.f, 0.f, 0.f};
        f32x4 acc1 = (f32x4){0.f, 0.f, 0.f, 0.f};
#pragma unroll
        for (int ks = 0; ks < 32; ks += 2) {
            bf16x8 a0 = *(const bf16x8*)&hA[l16 * 1024 + (((ks * 4 + q) ^ (l16 & 7)) * 8)];
            bf16x8 b0 = *(const bf16x8*)&Ws[brow * 1024 + (((ks * 4 + q) ^ (brow & 7)) * 8)];
            acc0 = __builtin_amdgcn_mfma_f32_16x16x32_bf16(a0, b0, acc0, 0, 0, 0);
            bf16x8 a1 = *(const bf16x8*)&hA[l16 * 1024 + ((((ks + 1) * 4 + q) ^ (l16 & 7)) * 8)];
            bf16x8 b1 = *(const bf16x8*)&Ws[brow * 1024 + ((((ks + 1) * 4 + q) ^ (brow & 7)) * 8)];
            acc1 = __builtin_amdgcn_mfma_f32_16x16x32_bf16(a1, b1, acc1, 0, 0, 0);
        }

        // epilogue: tanh (branch-free via exp), asm short stores (write-through, no CAS)
        unsigned short* hdst = hs + (size_t)(t + 1) * HB;
#pragma unroll
        for (int i = 0; i < 4; ++i) {
            float v = acc0[i] + acc1[i] + xiv[i];
            float e = __expf(2.f * v);
            unsigned int hv16 = f2bf(1.f - 2.f / (e + 1.f));
            const unsigned short* ap = &hdst[(r0 + q * 4 + i) * H_ + ncol];
            asm volatile("global_store_short %0, %1, off sc0 sc1"
                         :: "v"(ap), "v"(hv16) : "memory");
        }
        asm volatile("s_waitcnt vmcnt(0)" ::: "memory");   // wave's stores globally visible
        if (lane == 0)
            __hip_atomic_store(&flags[fbase + t * PRODS + pid], 1,
                               __ATOMIC_RELAXED, __HIP_MEMORY_SCOPE_AGENT);
    }
}

// ---------------- h_last: hs slot S -> fp32 ----------------
__global__ void k_hlast(const unsigned short* __restrict__ hsS, float* __restrict__ out) {
    int i = blockIdx.x * blockDim.x + threadIdx.x;
    if (i < HB) out[i] = bf2f(hsS[i]);
}

extern "C" void kernel_launch(void* const* d_in, const int* in_sizes, int n_in,
                              void* d_out, int out_size, void* d_ws, size_t ws_size,
                              hipStream_t stream) {
    const float* x  = (const float*)d_in[0];
    const float* Wi = (const float*)d_in[1];
    const float* bi = (const float*)d_in[2];
    const float* Wh = (const float*)d_in[3];
    const float* bh = (const float*)d_in[4];
    const float* Wo = (const float*)d_in[5];
    const float* bo = (const float*)d_in[6];
    float* out = (float*)d_out;

    char* p = (char*)d_ws;
    unsigned short* x_bf  = (unsigned short*)p; p += (size_t)B_ * S_ * I_ * 2;
    unsigned short* Wi_bf = (unsigned short*)p; p += (size_t)H_ * I_ * 2;
    unsigned short* Wh_bf = (unsigned short*)p; p += (size_t)H_ * H_ * 2;
    unsigned short* Wo_bf = (unsigned short*)p; p += (size_t)O_ * H_ * 2;
    unsigned short* xi    = (unsigned short*)p; p += (size_t)S_ * B_ * H_ * 2;
    unsigned short* hs    = (unsigned short*)p; p += (size_t)(S_ + 1) * HB * 2;
    int* flags = (int*)p;                                                  // 512 KB

    int n4;
    n4 = B_ * S_ * I_ / 4;
    k_f2bf4<<<(n4 + 255) / 256, 256, 0, stream>>>((const float4*)x,  (ushort4*)x_bf,  n4);
    n4 = H_ * I_ / 4;
    k_f2bf4<<<(n4 + 255) / 256, 256, 0, stream>>>((const float4*)Wi, (ushort4*)Wi_bf, n4);
    n4 = H_ * H_ / 4;
    k_f2bf4<<<(n4 + 255) / 256, 256, 0, stream>>>((const float4*)Wh, (ushort4*)Wh_bf, n4);
    n4 = O_ * H_ / 4;
    k_f2bf4<<<(n4 + 255) / 256, 256, 0, stream>>>((const float4*)Wo, (ushort4*)Wo_bf, n4);
    k_init<<<512, 256, 0, stream>>>(hs, flags);   // 131072 threads: hs slot0 + all flags

    // xi = x * Wi^T + bi + bh   (M=32768, N=1024, K=512)
    k_gemm<0><<<dim3(B_ * S_ / 128, H_ / 128), 256, 0, stream>>>(
        x_bf, Wi_bf, bi, bh, (void*)xi, B_ * S_, H_, I_);

    // sequential scan: 64 blocks = 4 batch-groups x 16 col-blocks, 160 KiB dynamic LDS
    (void)hipFuncSetAttribute((const void*)k_scan,
                              hipFuncAttributeMaxDynamicSharedMemorySize, 160 * 1024);
    k_scan<<<64, 256, 160 * 1024, stream>>>(xi, Wh_bf, hs, flags);

    // out = hs * Wo^T + bo      (M=32768, N=512, K=1024)
    k_gemm<1><<<dim3(B_ * S_ / 128, O_ / 128), 256, 0, stream>>>(
        hs + HB, Wo_bf, bo, nullptr, (void*)out, B_ * S_, O_, H_);

    // h_last
    k_hlast<<<(HB + 255) / 256, 256, 0, stream>>>(hs + (size_t)S_ * HB, out + (size_t)B_ * S_ * O_);
}

// Round 5
// 1671.357 us; speedup vs baseline: 2.9280x; 1.3861x over previous
//
#include <hip/hip_runtime.h>
#include <stdint.h>

#define B_ 64
#define S_ 512
#define I_ 512
#define H_ 1024
#define O_ 512
#define HB (B_ * H_)     // 65536 elements per hs slot
#define SENT 0x7F80u     // bf16 +inf: tanh output can never equal this

typedef __attribute__((ext_vector_type(8))) short bf16x8;   // 8 bf16 in 4 VGPRs
typedef __attribute__((ext_vector_type(4))) float f32x4;

__device__ inline unsigned short f2bf(float f) {
    union { float f; unsigned u; } v; v.f = f;
    unsigned r = v.u + 0x7fffu + ((v.u >> 16) & 1u);   // RNE
    return (unsigned short)(r >> 16);
}
__device__ inline float bf2f(unsigned short h) {
    union { unsigned u; float f; } v; v.u = ((unsigned)h) << 16; return v.f;
}
// nonzero iff either 16-bit half of w equals SENT
__device__ inline unsigned sentchk(unsigned w) {
    unsigned x = w ^ 0x7F807F80u;                       // halves==0 where sentinel
    return (x - 0x00010001u) & ~x & 0x80008000u;        // has-zero-halfword idiom
}

// ---------------- fp32 -> bf16 convert (x4 vectorized) ----------------
__global__ void k_f2bf4(const float4* __restrict__ src, ushort4* __restrict__ dst, int n4) {
    int i = blockIdx.x * blockDim.x + threadIdx.x;
    if (i < n4) {
        float4 v = src[i];
        ushort4 o;
        o.x = f2bf(v.x); o.y = f2bf(v.y); o.z = f2bf(v.z); o.w = f2bf(v.w);
        dst[i] = o;
    }
}

// ---------------- init: hs slot 0 = 0 (h0), slots 1..S = sentinel ----------------
__global__ void k_init(uint4* __restrict__ hs) {
    size_t i = (size_t)blockIdx.x * blockDim.x + threadIdx.x;   // one uint4 = 8 bf16
    size_t n = (size_t)(S_ + 1) * HB / 8;
    if (i >= n) return;
    unsigned v = (i < HB / 8) ? 0u : (SENT | (SENT << 16));
    hs[i] = (uint4){v, v, v, v};
}

// ---------------- generic 128x128 bf16 MFMA GEMM: C = A(MxK) * B(NxK)^T ----------------
template <int MODE>
__global__ __launch_bounds__(256) void k_gemm(
    const unsigned short* __restrict__ A, const unsigned short* __restrict__ Bm,
    const float* __restrict__ bias1, const float* __restrict__ bias2,
    void* __restrict__ Cout, int M, int N, int K)
{
    __shared__ unsigned short As[128][40];
    __shared__ unsigned short Bs[128][40];

    const int tid  = threadIdx.x;
    const int m0   = blockIdx.x * 128;
    const int n0   = blockIdx.y * 128;
    const int wave = tid >> 6, lane = tid & 63;
    const int wm   = (wave >> 1) * 64, wn = (wave & 1) * 64;
    const int l16  = lane & 15, q = lane >> 4;

    f32x4 acc[4][4];
#pragma unroll
    for (int a = 0; a < 4; ++a)
#pragma unroll
        for (int b = 0; b < 4; ++b)
            acc[a][b] = (f32x4){0.f, 0.f, 0.f, 0.f};

    for (int k0 = 0; k0 < K; k0 += 32) {
#pragma unroll
        for (int c = 0; c < 2; ++c) {
            int idx = tid + c * 256;
            int row = idx >> 2, col = (idx & 3) * 8;
            *(bf16x8*)&As[row][col] = *(const bf16x8*)&A [(m0 + row) * K + k0 + col];
            *(bf16x8*)&Bs[row][col] = *(const bf16x8*)&Bm[(n0 + row) * K + k0 + col];
        }
        __syncthreads();

        bf16x8 af[4], bfr[4];
#pragma unroll
        for (int mt = 0; mt < 4; ++mt) af[mt]  = *(const bf16x8*)&As[wm + mt * 16 + l16][q * 8];
#pragma unroll
        for (int nt = 0; nt < 4; ++nt) bfr[nt] = *(const bf16x8*)&Bs[wn + nt * 16 + l16][q * 8];
#pragma unroll
        for (int mt = 0; mt < 4; ++mt)
#pragma unroll
            for (int nt = 0; nt < 4; ++nt)
                acc[mt][nt] = __builtin_amdgcn_mfma_f32_16x16x32_bf16(af[mt], bfr[nt], acc[mt][nt], 0, 0, 0);
        __syncthreads();
    }

    // epilogue; C/D layout: col = lane&15, row = (lane>>4)*4 + reg
#pragma unroll
    for (int mt = 0; mt < 4; ++mt) {
#pragma unroll
        for (int nt = 0; nt < 4; ++nt) {
            int gn = n0 + wn + nt * 16 + l16;
#pragma unroll
            for (int i = 0; i < 4; ++i) {
                int gm = m0 + wm + mt * 16 + q * 4 + i;
                float v = acc[mt][nt][i];
                if (MODE == 0) {
                    v += bias1[gn] + bias2[gn];
                    int bb = gm >> 9, s = gm & (S_ - 1);       // gm = b*S+s
                    ((unsigned short*)Cout)[(s * B_ + bb) * H_ + gn] = f2bf(v);
                } else {
                    v += bias1[gn];
                    int t = gm >> 6, bb = gm & (B_ - 1);        // gm = t*B+b
                    ((float*)Cout)[((bb << 9) + t) * O_ + gn] = v;
                }
            }
        }
    }
}

// ---------------- sequential scan: h_{t+1} = tanh(xi_t + h_t * Wh^T) ----------------
// 4 batch-groups x 16 col-blocks. NO flags, NO fences, NO store drains: hs slots are
// pre-filled with bf16 +inf sentinel; consumers poll-load their 8 KB wave-slice
// (asm b128 sc0 sc1, MALL-coherent) and retry while any element is still sentinel.
// Each 2B location transitions sentinel->value exactly once, so partial visibility
// is safe. Producers fire 4 global_store_short sc0 sc1 and move on.
__global__ __launch_bounds__(256, 1) void k_scan(
    const unsigned short* __restrict__ xi,   // (S,B,H) bf16
    const unsigned short* __restrict__ Wh,   // (H,H) bf16
    unsigned short* __restrict__ hs)         // (S+1,B,H) bf16, slots 1..S = sentinel
{
    extern __shared__ char lds[];
    unsigned short* Ws = (unsigned short*)lds;                   // [64][1024] swizzled
    unsigned short* hA = (unsigned short*)(lds + 64 * 1024 * 2); // [16][1024] swizzled

    const int bid = blockIdx.x;
    const int g   = bid & 3;                 // batch group: rows 16g..16g+15
    const int j   = bid >> 2;                // col block:   cols 64j..64j+63
    const int n0  = j * 64;
    const int r0  = g * 16;
    const int tid = threadIdx.x;
    const int wave = tid >> 6, lane = tid & 63;
    const int l16 = lane & 15, q = lane >> 4;

    // stage Wh rows n0..n0+63, swizzled: chunk (row, cc) at cc^(row&7)
    for (int c = tid; c < 8192; c += 256) {
        int row = c >> 7, cc = c & 127;
        *(bf16x8*)&Ws[row * 1024 + ((cc ^ (row & 7)) * 8)] =
            *(const bf16x8*)&Wh[(n0 + row) * H_ + cc * 8];
    }
    __syncthreads();

    const int brow = wave * 16 + l16;        // Ws row for B-fragment
    const int ncol = n0 + wave * 16 + l16;   // output column this lane owns

    for (int t = 0; t < S_; ++t) {
        // xi prefetch (plain cached loads; read-only stream)
        const unsigned short* xit = xi + (size_t)t * HB;
        float xiv[4];
#pragma unroll
        for (int i = 0; i < 4; ++i)
            xiv[i] = bf2f(xit[(r0 + q * 4 + i) * H_ + ncol]);

        // poll-load own 8 KB wave-slice of h_t until sentinel-free (one pipelined
        // MALL round trip per attempt; doubles as the sync AND the data fetch)
        const char* hb = (const char*)(hs + (size_t)t * HB + (size_t)r0 * H_)
                         + (size_t)wave * 8192;
        uint4 hv[8];
        for (;;) {
#pragma unroll
            for (int k = 0; k < 8; ++k) {
                const char* a = hb + (size_t)(k * 64 + lane) * 16;
                asm volatile("global_load_dwordx4 %0, %1, off sc0 sc1"
                             : "=v"(hv[k]) : "v"(a));
            }
            asm volatile("s_waitcnt vmcnt(0)" ::: "memory");
            unsigned bad = 0;
#pragma unroll
            for (int k = 0; k < 8; ++k) {
                bad |= sentchk(hv[k].x); bad |= sentchk(hv[k].y);
                bad |= sentchk(hv[k].z); bad |= sentchk(hv[k].w);
            }
            if (__ballot(bad != 0) == 0ull) break;
        }
        // stage slice into swizzled LDS
#pragma unroll
        for (int k = 0; k < 8; ++k) {
            int ci = wave * 512 + k * 64 + lane;
            int row = ci >> 7, cc = ci & 127;
            *(uint4*)&hA[row * 1024 + ((cc ^ (row & 7)) * 8)] = hv[k];
        }
        __syncthreads();   // all slices staged before any fragment reads

        // 32 MFMAs, 4 accumulators (8-deep dependent chains)
        f32x4 acc[4];
#pragma unroll
        for (int a = 0; a < 4; ++a) acc[a] = (f32x4){0.f, 0.f, 0.f, 0.f};
#pragma unroll
        for (int ks = 0; ks < 32; ++ks) {
            bf16x8 av = *(const bf16x8*)&hA[l16 * 1024 + (((ks * 4 + q) ^ (l16 & 7)) * 8)];
            bf16x8 bv = *(const bf16x8*)&Ws[brow * 1024 + (((ks * 4 + q) ^ (brow & 7)) * 8)];
            acc[ks & 3] = __builtin_amdgcn_mfma_f32_16x16x32_bf16(av, bv, acc[ks & 3], 0, 0, 0);
        }
        __syncthreads();   // all fragment reads done before next step overwrites hA

        // epilogue: tanh (branch-free), fire-and-forget write-through stores
        unsigned short* hdst = hs + (size_t)(t + 1) * HB;
#pragma unroll
        for (int i = 0; i < 4; ++i) {
            float v = acc[0][i] + acc[1][i] + acc[2][i] + acc[3][i] + xiv[i];
            float e = __expf(2.f * v);
            unsigned int hv16 = f2bf(1.f - 2.f / (e + 1.f));
            const unsigned short* ap = &hdst[(r0 + q * 4 + i) * H_ + ncol];
            asm volatile("global_store_short %0, %1, off sc0 sc1"
                         :: "v"(ap), "v"(hv16) : "memory");
        }
        // no drain: next poll's vmcnt(0) covers them; visibility is eventual
    }
}

// ---------------- h_last: hs slot S -> fp32 ----------------
__global__ void k_hlast(const unsigned short* __restrict__ hsS, float* __restrict__ out) {
    int i = blockIdx.x * blockDim.x + threadIdx.x;
    if (i < HB) out[i] = bf2f(hsS[i]);
}

extern "C" void kernel_launch(void* const* d_in, const int* in_sizes, int n_in,
                              void* d_out, int out_size, void* d_ws, size_t ws_size,
                              hipStream_t stream) {
    const float* x  = (const float*)d_in[0];
    const float* Wi = (const float*)d_in[1];
    const float* bi = (const float*)d_in[2];
    const float* Wh = (const float*)d_in[3];
    const float* bh = (const float*)d_in[4];
    const float* Wo = (const float*)d_in[5];
    const float* bo = (const float*)d_in[6];
    float* out = (float*)d_out;

    char* p = (char*)d_ws;
    unsigned short* x_bf  = (unsigned short*)p; p += (size_t)B_ * S_ * I_ * 2;
    unsigned short* Wi_bf = (unsigned short*)p; p += (size_t)H_ * I_ * 2;
    unsigned short* Wh_bf = (unsigned short*)p; p += (size_t)H_ * H_ * 2;
    unsigned short* Wo_bf = (unsigned short*)p; p += (size_t)O_ * H_ * 2;
    unsigned short* xi    = (unsigned short*)p; p += (size_t)S_ * B_ * H_ * 2;
    unsigned short* hs    = (unsigned short*)p; p += (size_t)(S_ + 1) * HB * 2;

    int n4;
    n4 = B_ * S_ * I_ / 4;
    k_f2bf4<<<(n4 + 255) / 256, 256, 0, stream>>>((const float4*)x,  (ushort4*)x_bf,  n4);
    n4 = H_ * I_ / 4;
    k_f2bf4<<<(n4 + 255) / 256, 256, 0, stream>>>((const float4*)Wi, (ushort4*)Wi_bf, n4);
    n4 = H_ * H_ / 4;
    k_f2bf4<<<(n4 + 255) / 256, 256, 0, stream>>>((const float4*)Wh, (ushort4*)Wh_bf, n4);
    n4 = O_ * H_ / 4;
    k_f2bf4<<<(n4 + 255) / 256, 256, 0, stream>>>((const float4*)Wo, (ushort4*)Wo_bf, n4);

    // hs: slot 0 = zeros, slots 1..S = bf16 +inf sentinel
    {
        size_t n = (size_t)(S_ + 1) * HB / 8;
        k_init<<<(unsigned)((n + 255) / 256), 256, 0, stream>>>((uint4*)hs);
    }

    // xi = x * Wi^T + bi + bh   (M=32768, N=1024, K=512)
    k_gemm<0><<<dim3(B_ * S_ / 128, H_ / 128), 256, 0, stream>>>(
        x_bf, Wi_bf, bi, bh, (void*)xi, B_ * S_, H_, I_);

    // sequential scan: 64 blocks = 4 batch-groups x 16 col-blocks, 160 KiB dynamic LDS
    (void)hipFuncSetAttribute((const void*)k_scan,
                              hipFuncAttributeMaxDynamicSharedMemorySize, 160 * 1024);
    k_scan<<<64, 256, 160 * 1024, stream>>>(xi, Wh_bf, hs);

    // out = hs * Wo^T + bo      (M=32768, N=512, K=1024)
    k_gemm<1><<<dim3(B_ * S_ / 128, O_ / 128), 256, 0, stream>>>(
        hs + HB, Wo_bf, bo, nullptr, (void*)out, B_ * S_, O_, H_);

    // h_last
    k_hlast<<<(HB + 255) / 256, 256, 0, stream>>>(hs + (size_t)S_ * HB, out + (size_t)B_ * S_ * O_);
}